// Round 7
// baseline (158.606 us; speedup 1.0000x reference)
//
#include <hip/hip_runtime.h>
#include <math.h>

// ProxyNCA loss, MFMA + LDS-staged class-sweep.
// logit_ic = 18 * xhat_i . phat_c ;  nll_i = log(sum_c exp(logit_ic)) - logit_{i,T_i}
// Both operands prescaled by sqrt(18*log2(e)) in bf16; 16x16x32 bf16 MFMA acc
// holds log2(e)*logit, so exp = v_exp_f32 directly.
// Round 7 vs round 6: round 6 streamed P per-wave from global (8MB > L2) ->
// exposed L3 latency every chunk (MfmaUtil 11%, VALU 17%, both idle).
// Now: canonical GEMM staging.
//  - k_prep_p writes Pb PRE-PACKED in MFMA fragment order [chunk][frag][lane][16B]
//    -> global_load_lds staging is a linear identity copy (legal dest layout),
//    ds_read_b128 is lane-contiguous (conflict-free), no swizzle needed.
//  - 2-phase double-buffered pipeline: STAGE(next tile) -> compute(cur) ->
//    barrier (T3-minimal). 8 waves share each staged tile via LDS.
//  - wave owns 64 rows (8 MFMA per 2 ds_reads); block = 512 rows x 1024 cls.
//  - sp = bx&63 so the 8 row-blocks sharing a P-slice land on one XCD (%8).

#define NROWS 4096
#define NCLS  65536
#define DIM   64
#define NSPLIT 64                     // class splits
#define NRB    8                      // row blocks (grid = 512)
#define CPS   (NCLS / 16 / NSPLIT)    // 64 chunks (of 16 classes) per split
#define TILE   8                      // chunks per LDS stage (16 KB)
#define NT    (CPS / TILE)            // 8 tiles per block

typedef __attribute__((ext_vector_type(8))) short short8;
typedef __attribute__((ext_vector_type(4))) float f32x4;

#define PRESCALE 5.0959308f           // sqrt(18 * log2(e))

__device__ __forceinline__ short bf16rne(float f) {
    union { float f; unsigned u; } v; v.f = f;
    unsigned r = (v.u + 0x7fffu + ((v.u >> 16) & 1u)) >> 16;
    return (short)r;
}

// ---- proxies -> prescaled-normalized bf16, packed in MFMA A-frag order ----
// Pb ushort index for (class row, dim d):
//   chunk = row>>4, frag = d>>5, lane = (row&15) + 16*((d>>3)&3), elem = d&7
//   idx = chunk*1024 + frag*512 + lane*8 + elem
__global__ void k_prep_p(const float* __restrict__ P, unsigned short* __restrict__ Pb) {
    int row = blockIdx.x * 4 + (threadIdx.x >> 6);
    int d   = threadIdx.x & 63;
    float v  = P[row * DIM + d];
    float sq = v * v;
    #pragma unroll
    for (int off = 32; off > 0; off >>= 1) sq += __shfl_xor(sq, off);
    float sc = PRESCALE * rsqrtf(fmaxf(sq, 1e-24f));
    int idx = (row >> 4) * 1024 + (d >> 5) * 512
            + ((row & 15) + ((d >> 3) & 3) * 16) * 8 + (d & 7);
    Pb[idx] = (unsigned short)bf16rne(v * sc);
}

// ---- X -> bf16 frags (row-major) + exact-f32 target logit ---------------
__global__ void k_prep(const float* __restrict__ X, const float* __restrict__ P,
                       const int* __restrict__ T,
                       unsigned short* __restrict__ Xb, float* __restrict__ st) {
    int row  = blockIdx.x * 4 + (threadIdx.x >> 6);
    int lane = threadIdx.x & 63;
    int tc   = T[row];
    float xv = X[row * DIM + lane];
    float pv = P[tc  * DIM + lane];
    float x2 = xv * xv, p2 = pv * pv, xp = xv * pv;
    #pragma unroll
    for (int off = 32; off > 0; off >>= 1) {
        x2 += __shfl_xor(x2, off);
        p2 += __shfl_xor(p2, off);
        xp += __shfl_xor(xp, off);
    }
    float rx = rsqrtf(fmaxf(x2, 1e-24f));
    Xb[row * DIM + lane] = (unsigned short)bf16rne(xv * (PRESCALE * rx));
    if (lane == 0)
        st[row] = 18.0f * xp * rx * rsqrtf(fmaxf(p2, 1e-24f));
}

// ---- main: block (rb=bx>>6, sp=bx&63): rows [rb*512,+512) x classes [sp*1024,+1024)
// wave w owns 64 rows (4 MFMA row-tiles, X fixed in 32 VGPRs).
// P staged tile-by-tile (8 chunks = 16 KB) via global_load_lds, double-buffered.
__global__ __launch_bounds__(512, 4)
void k_main(const unsigned short* __restrict__ Pb, const unsigned short* __restrict__ Xb,
            float* __restrict__ psum) {
    __shared__ __align__(16) unsigned short lds[2][TILE * 1024];  // 2 x 16 KB

    int t  = threadIdx.x;
    int w  = t >> 6;
    int l  = t & 63;
    int bx = blockIdx.x;
    int rb = bx >> 6;
    int sp = bx & 63;
    int lm = l & 15;
    int lk = l >> 4;

    int rowbase = rb * 512 + w * 64;
    short8 x[4][2];
    #pragma unroll
    for (int rt = 0; rt < 4; ++rt) {
        x[rt][0] = *reinterpret_cast<const short8*>(Xb + (rowbase + rt * 16 + lm) * DIM + lk * 8);
        x[rt][1] = *reinterpret_cast<const short8*>(Xb + (rowbase + rt * 16 + lm) * DIM + 32 + lk * 8);
    }

    const char* gsrc = reinterpret_cast<const char*>(Pb) + (size_t)sp * (CPS * 2048);

    float ea[4][4];
    #pragma unroll
    for (int i = 0; i < 4; ++i)
        #pragma unroll
        for (int j = 0; j < 4; ++j) ea[i][j] = 0.0f;

    const f32x4 zero = {0.0f, 0.0f, 0.0f, 0.0f};

    // stage tile tl into buffer buf: linear copy of 16 KB, 2 calls/wave of
    // (64 lanes x 16B); LDS dest wave-uniform base, HW adds lane*16.
    #define STAGE(buf, tl) do {                                                   \
        const char* s0_ = gsrc + (tl) * (TILE * 2048) + w * 1024 + l * 16;        \
        __builtin_amdgcn_global_load_lds(                                         \
            (const __attribute__((address_space(1))) unsigned int*)s0_,           \
            (__attribute__((address_space(3))) unsigned int*)((char*)&lds[buf][0] + w * 1024), \
            16, 0, 0);                                                            \
        __builtin_amdgcn_global_load_lds(                                         \
            (const __attribute__((address_space(1))) unsigned int*)(s0_ + 8192),  \
            (__attribute__((address_space(3))) unsigned int*)((char*)&lds[buf][0] + 8192 + w * 1024), \
            16, 0, 0);                                                            \
    } while (0)

    STAGE(0, 0);
    __syncthreads();                  // compiler drains vmcnt before barrier

    #pragma unroll 1
    for (int tl = 0; tl < NT; ++tl) {
        if (tl + 1 < NT) STAGE((tl + 1) & 1, tl + 1);

        const char* lb = (const char*)&lds[tl & 1][0];
        #pragma unroll
        for (int c = 0; c < TILE; ++c) {
            short8 p0 = *reinterpret_cast<const short8*>(lb + c * 2048 + l * 16);
            short8 p1 = *reinterpret_cast<const short8*>(lb + c * 2048 + 1024 + l * 16);
            #pragma unroll
            for (int rt = 0; rt < 4; ++rt) {
                f32x4 acc = __builtin_amdgcn_mfma_f32_16x16x32_bf16(p0, x[rt][0], zero, 0, 0, 0);
                acc = __builtin_amdgcn_mfma_f32_16x16x32_bf16(p1, x[rt][1], acc, 0, 0, 0);
                ea[rt][0] += __builtin_amdgcn_exp2f(acc[0]);
                ea[rt][1] += __builtin_amdgcn_exp2f(acc[1]);
                ea[rt][2] += __builtin_amdgcn_exp2f(acc[2]);
                ea[rt][3] += __builtin_amdgcn_exp2f(acc[3]);
            }
        }
        __syncthreads();              // stage(next) done + all reads of cur done
    }

    // once-per-wave: reduce lk-groups, store 4 row-tiles
    #pragma unroll
    for (int rt = 0; rt < 4; ++rt) {
        float s = (ea[rt][0] + ea[rt][1]) + (ea[rt][2] + ea[rt][3]);
        s += __shfl_xor(s, 16);
        s += __shfl_xor(s, 32);
        if (l < 16) psum[sp * NROWS + rowbase + rt * 16 + l] = s;
    }
    #undef STAGE
}

// ---- per-row: nll[r] = log(sum_sp psum[sp][r]) - st[r] ------------------
__global__ void k_rowred(const float* __restrict__ psum, const float* __restrict__ st,
                         float* __restrict__ nll) {
    int r = blockIdx.x * 256 + threadIdx.x;
    float s = 0.0f;
    #pragma unroll 8
    for (int i = 0; i < NSPLIT; ++i)
        s += psum[i * NROWS + r];
    nll[r] = logf(s) - st[r];
}

// ---- mean over rows -----------------------------------------------------
__global__ void k_final(const float* __restrict__ nll, float* __restrict__ out) {
    __shared__ float red[256];
    int t = threadIdx.x;
    float acc = 0.0f;
    for (int r = t; r < NROWS; r += 256) acc += nll[r];
    red[t] = acc;
    __syncthreads();
    #pragma unroll
    for (int off = 128; off > 0; off >>= 1) {
        if (t < off) red[t] += red[t + off];
        __syncthreads();
    }
    if (t == 0) out[0] = red[0] / (float)NROWS;
}

extern "C" void kernel_launch(void* const* d_in, const int* in_sizes, int n_in,
                              void* d_out, int out_size, void* d_ws, size_t ws_size,
                              hipStream_t stream) {
    const float* X = (const float*)d_in[0];
    const float* P = (const float*)d_in[1];
    const int*   T = (const int*)  d_in[3];   // d_in[2] = indices (unused)
    float* out = (float*)d_out;

    char* ws = (char*)d_ws;
    unsigned short* Xb = (unsigned short*)ws;                 // 512 KB
    float* st   = (float*)(ws + (512 << 10));                 // 16 KB
    float* nll  = (float*)(ws + (528 << 10));                 // 16 KB
    unsigned short* Pb = (unsigned short*)(ws + (1 << 20));   // 8 MB (packed frags)
    float* psum = (float*)(ws + (9 << 20));                   // 1 MB (64 x 4096)

    k_prep_p<<<NCLS / 4, 256, 0, stream>>>(P, Pb);
    k_prep  <<<NROWS / 4, 256, 0, stream>>>(X, P, T, Xb, st);
    k_main  <<<NRB * NSPLIT, 512, 0, stream>>>(Pb, Xb, psum);
    k_rowred<<<NROWS / 256, 256, 0, stream>>>(psum, st, nll);
    k_final <<<1, 256, 0, stream>>>(nll, out);
}

// Round 8
// 103.051 us; speedup vs baseline: 1.5391x; 1.5391x over previous
//
#include <hip/hip_runtime.h>
#include <math.h>

// ProxyNCA loss, MFMA version — round 8.
// logit_ic = 18 * xhat_i . phat_c ;  nll_i = log(sum_c exp(logit_ic)) - logit_{i,T_i}
// Both operands prescaled by sqrt(18*log2(e)) = 5.0959308 into bf16; the
// 16x16x32 bf16 MFMA accumulator holds log2(e)*logit, so exp = v_exp_f32.
//
// Round 8 = revert to round 3's structure (best measured: 68.6us k_main,
// no spill, FETCH 10MB) + targeted micro-fixes for its measured VALU excess:
//  - hoisted zero f32x4 (R3 re-zeroed the acc quad per chunk: 32 v_mov/tile)
//  - one-tile-ahead register prefetch of the 2 Xb fragments (R3 exposed
//    ~200cyc L2 latency per tile; +8 VGPR only, ~100 total < 128 cap)
//  - 4 independent exp-accumulator chains (R3 had 2)
//  - pointer-increment addressing for the row sweep
//  - k_rowred does the final mean via per-block atomicAdd (k_final removed;
//    out zeroed with hipMemsetAsync — graph-capture legal)
// Lessons kept: NO launch_bounds tighter than VGPR need (R4/R7 spills);
// stream only the small operand (Xb 512KB, L2-resident); P stays in regs.

#define NROWS 4096
#define NCLS  65536
#define DIM   64
#define CBLK  128                 // classes per block (register-resident P frags)
#define NBLK  (NCLS / CBLK)       // 512 blocks = 2/CU
#define NCH   (CBLK / 16)         // 8 MFMA chunks of 16 classes

typedef __attribute__((ext_vector_type(8))) short short8;
typedef __attribute__((ext_vector_type(4))) float f32x4;

#define PRESCALE 5.0959308f       // sqrt(18 * log2(e))

__device__ __forceinline__ short bf16rne(float f) {
    union { float f; unsigned u; } v; v.f = f;
    unsigned r = (v.u + 0x7fffu + ((v.u >> 16) & 1u)) >> 16;
    return (short)r;
}

// ---- per-row prep: Xb = bf16(PRESCALE * xhat), st[r] = exact f32 target logit
__global__ void k_prep(const float* __restrict__ X, const float* __restrict__ P,
                       const int* __restrict__ T,
                       unsigned short* __restrict__ Xb, float* __restrict__ st) {
    int row  = blockIdx.x * 4 + (threadIdx.x >> 6);
    int lane = threadIdx.x & 63;
    int tc   = T[row];
    float xv = X[row * DIM + lane];
    float pv = P[tc  * DIM + lane];
    float x2 = xv * xv, p2 = pv * pv, xp = xv * pv;
    #pragma unroll
    for (int off = 32; off > 0; off >>= 1) {
        x2 += __shfl_xor(x2, off);
        p2 += __shfl_xor(p2, off);
        xp += __shfl_xor(xp, off);
    }
    float rx = rsqrtf(fmaxf(x2, 1e-24f));
    Xb[row * DIM + lane] = (unsigned short)bf16rne(xv * (PRESCALE * rx));
    if (lane == 0)
        st[row] = 18.0f * xp * rx * rsqrtf(fmaxf(p2, 1e-24f));
}

// ---- main: block b owns classes [b*128,(b+1)*128); sweeps all 4096 rows ----
// 8 waves; wave w handles row-tiles w, w+8, ... (32 tiles of 16 rows).
// P frags normalized/converted once into 64 regs per wave.
// mfma(P_frag, X_frag): C col = lane&15 = x-row, regs = 4 classes.
__global__ __launch_bounds__(512, 4)
void k_main(const float* __restrict__ prox, const unsigned short* __restrict__ Xb,
            float* __restrict__ psum) {
    int t = threadIdx.x;
    int w = t >> 6;
    int l = t & 63;
    int cb = blockIdx.x * CBLK;
    int lm = l & 15;         // class-in-chunk (A row) / x-row (B col)
    int lk = l >> 4;         // k-group

    // ---- one-time: load 128 classes of P (f32), normalize, convert to frags
    short8 pb[NCH][2];
    #pragma unroll
    for (int ch = 0; ch < NCH; ++ch) {
        int cls = cb + ch * 16 + lm;
        const float4* pr = reinterpret_cast<const float4*>(prox + cls * DIM + lk * 8);
        float4 a0 = pr[0], a1 = pr[1];          // k = lk*8 .. +7
        const float4* pr2 = reinterpret_cast<const float4*>(prox + cls * DIM + 32 + lk * 8);
        float4 b0 = pr2[0], b1 = pr2[1];        // k = 32 + lk*8 .. +7
        float sq = a0.x*a0.x + a0.y*a0.y + a0.z*a0.z + a0.w*a0.w
                 + a1.x*a1.x + a1.y*a1.y + a1.z*a1.z + a1.w*a1.w
                 + b0.x*b0.x + b0.y*b0.y + b0.z*b0.z + b0.w*b0.w
                 + b1.x*b1.x + b1.y*b1.y + b1.z*b1.z + b1.w*b1.w;
        sq += __shfl_xor(sq, 16);
        sq += __shfl_xor(sq, 32);
        float sc = PRESCALE * rsqrtf(fmaxf(sq, 1e-24f));
        short8 f0, f1;
        f0[0]=bf16rne(a0.x*sc); f0[1]=bf16rne(a0.y*sc); f0[2]=bf16rne(a0.z*sc); f0[3]=bf16rne(a0.w*sc);
        f0[4]=bf16rne(a1.x*sc); f0[5]=bf16rne(a1.y*sc); f0[6]=bf16rne(a1.z*sc); f0[7]=bf16rne(a1.w*sc);
        f1[0]=bf16rne(b0.x*sc); f1[1]=bf16rne(b0.y*sc); f1[2]=bf16rne(b0.z*sc); f1[3]=bf16rne(b0.w*sc);
        f1[4]=bf16rne(b1.x*sc); f1[5]=bf16rne(b1.y*sc); f1[6]=bf16rne(b1.z*sc); f1[7]=bf16rne(b1.w*sc);
        pb[ch][0] = f0;
        pb[ch][1] = f1;
    }

    const f32x4 zero = {0.0f, 0.0f, 0.0f, 0.0f};

    // ---- row sweep: 32 tiles of 16 rows, stride 128 rows, 1-tile prefetch
    // tile i rows = (w + 8*i)*16; address delta per i = 8192 shorts = 1024 short8
    const short8* xp = reinterpret_cast<const short8*>(Xb + (w * 16 + lm) * DIM + lk * 8);
    short8 xb0 = xp[0];            // k 0..31 fragment
    short8 xb1 = xp[4];            // k 32..63 fragment (+32 shorts)
    float* prow = psum + blockIdx.x * NROWS + w * 16 + l;   // valid when l<16

    #pragma unroll 2
    for (int it = 0; it < 32; ++it) {
        const short8* xn = (it < 31) ? (xp + 1024) : xp;    // last iter: dummy reload
        short8 n0 = xn[0];
        short8 n1 = xn[4];

        float e0 = 0.f, e1 = 0.f, e2 = 0.f, e3 = 0.f;
        #pragma unroll
        for (int ch = 0; ch < NCH; ++ch) {
            f32x4 c = __builtin_amdgcn_mfma_f32_16x16x32_bf16(pb[ch][0], xb0, zero, 0, 0, 0);
            c = __builtin_amdgcn_mfma_f32_16x16x32_bf16(pb[ch][1], xb1, c, 0, 0, 0);
            e0 += __builtin_amdgcn_exp2f(c[0]);
            e1 += __builtin_amdgcn_exp2f(c[1]);
            e2 += __builtin_amdgcn_exp2f(c[2]);
            e3 += __builtin_amdgcn_exp2f(c[3]);
        }
        float s = (e0 + e1) + (e2 + e3);
        s += __shfl_xor(s, 16);
        s += __shfl_xor(s, 32);
        if (l < 16) prow[it * 128] = s;     // rows advance 128/iter

        xp = xn; xb0 = n0; xb1 = n1;
    }
}

// ---- per-row finish + global mean: out += sum_r (log(sum_b psum[b][r]) - st[r]) / N
__global__ void k_rowred(const float* __restrict__ psum, const float* __restrict__ st,
                         float* __restrict__ out) {
    __shared__ float red[256];
    int t = threadIdx.x;
    int r = blockIdx.x * 256 + t;
    float s = 0.0f;
    #pragma unroll 8
    for (int i = 0; i < NBLK; ++i)
        s += psum[i * NROWS + r];
    red[t] = (logf(s) - st[r]) * (1.0f / (float)NROWS);
    __syncthreads();
    #pragma unroll
    for (int off = 128; off > 0; off >>= 1) {
        if (t < off) red[t] += red[t + off];
        __syncthreads();
    }
    if (t == 0) atomicAdd(out, red[0]);
}

extern "C" void kernel_launch(void* const* d_in, const int* in_sizes, int n_in,
                              void* d_out, int out_size, void* d_ws, size_t ws_size,
                              hipStream_t stream) {
    const float* X = (const float*)d_in[0];
    const float* P = (const float*)d_in[1];
    const int*   T = (const int*)  d_in[3];   // d_in[2] = indices (unused)
    float* out = (float*)d_out;

    char* ws = (char*)d_ws;
    unsigned short* Xb = (unsigned short*)ws;                 // 512 KB
    float* st   = (float*)(ws + (512 << 10));                 // 16 KB
    float* psum = (float*)(ws + (1 << 20));                   // 8 MB (512 x 4096 f32)

    hipMemsetAsync(out, 0, sizeof(float), stream);
    k_prep  <<<NROWS / 4, 256, 0, stream>>>(X, P, T, Xb, st);
    k_main  <<<NBLK, 512, 0, stream>>>(P, Xb, psum);
    k_rowred<<<NROWS / 256, 256, 0, stream>>>(psum, st, out);
}

// Round 9
// 94.012 us; speedup vs baseline: 1.6871x; 1.0962x over previous
//
#include <hip/hip_runtime.h>
#include <math.h>

// ProxyNCA loss, MFMA version — round 9.
// logit_ic = 18 * xhat_i . phat_c ;  nll_i = log(sum_c exp(logit_ic)) - logit_{i,T_i}
// Both operands prescaled by sqrt(18*log2(e)) = 5.0959308 into bf16; the
// 16x16x32 bf16 MFMA accumulator holds log2(e)*logit, so exp = v_exp_f32.
//
// Round 9 = round 8 with ONE change: __launch_bounds__(512,2).
// R8's (512,4) capped unified VGPR+AGPR at 128; with the MFMA acc portion
// split off, pb(64)+prefetch(16)+xb(16)+misc didn't fit the arch portion ->
// spill (WRITE 61MB, FETCH 37MB, 76us). Third spill incident (R2/R7/R8),
// all from launch-bounds caps; all no-spill configs were (512,2).
// At ~100-110 VGPR the HW still gives 4 waves/SIMD (<=128 step), so no
// occupancy loss vs R3 — we just stop fighting the register allocator.
// Keeps R8's: hoisted zero quad, 1-tile X prefetch, 4 exp chains, pointer
// increments, fused rowred+mean via atomicAdd.

#define NROWS 4096
#define NCLS  65536
#define DIM   64
#define CBLK  128                 // classes per block (register-resident P frags)
#define NBLK  (NCLS / CBLK)       // 512 blocks = 2/CU
#define NCH   (CBLK / 16)         // 8 MFMA chunks of 16 classes

typedef __attribute__((ext_vector_type(8))) short short8;
typedef __attribute__((ext_vector_type(4))) float f32x4;

#define PRESCALE 5.0959308f       // sqrt(18 * log2(e))

__device__ __forceinline__ short bf16rne(float f) {
    union { float f; unsigned u; } v; v.f = f;
    unsigned r = (v.u + 0x7fffu + ((v.u >> 16) & 1u)) >> 16;
    return (short)r;
}

// ---- per-row prep: Xb = bf16(PRESCALE * xhat), st[r] = exact f32 target logit
__global__ void k_prep(const float* __restrict__ X, const float* __restrict__ P,
                       const int* __restrict__ T,
                       unsigned short* __restrict__ Xb, float* __restrict__ st) {
    int row  = blockIdx.x * 4 + (threadIdx.x >> 6);
    int lane = threadIdx.x & 63;
    int tc   = T[row];
    float xv = X[row * DIM + lane];
    float pv = P[tc  * DIM + lane];
    float x2 = xv * xv, p2 = pv * pv, xp = xv * pv;
    #pragma unroll
    for (int off = 32; off > 0; off >>= 1) {
        x2 += __shfl_xor(x2, off);
        p2 += __shfl_xor(p2, off);
        xp += __shfl_xor(xp, off);
    }
    float rx = rsqrtf(fmaxf(x2, 1e-24f));
    Xb[row * DIM + lane] = (unsigned short)bf16rne(xv * (PRESCALE * rx));
    if (lane == 0)
        st[row] = 18.0f * xp * rx * rsqrtf(fmaxf(p2, 1e-24f));
}

// ---- main: block b owns classes [b*128,(b+1)*128); sweeps all 4096 rows ----
// 8 waves; wave w handles row-tiles w, w+8, ... (32 tiles of 16 rows).
// P frags normalized/converted once into 64 regs per wave.
// mfma(P_frag, X_frag): C col = lane&15 = x-row, regs = 4 classes.
__global__ __launch_bounds__(512, 2)
void k_main(const float* __restrict__ prox, const unsigned short* __restrict__ Xb,
            float* __restrict__ psum) {
    int t = threadIdx.x;
    int w = t >> 6;
    int l = t & 63;
    int cb = blockIdx.x * CBLK;
    int lm = l & 15;         // class-in-chunk (A row) / x-row (B col)
    int lk = l >> 4;         // k-group

    // ---- one-time: load 128 classes of P (f32), normalize, convert to frags
    short8 pb[NCH][2];
    #pragma unroll
    for (int ch = 0; ch < NCH; ++ch) {
        int cls = cb + ch * 16 + lm;
        const float4* pr = reinterpret_cast<const float4*>(prox + cls * DIM + lk * 8);
        float4 a0 = pr[0], a1 = pr[1];          // k = lk*8 .. +7
        const float4* pr2 = reinterpret_cast<const float4*>(prox + cls * DIM + 32 + lk * 8);
        float4 b0 = pr2[0], b1 = pr2[1];        // k = 32 + lk*8 .. +7
        float sq = a0.x*a0.x + a0.y*a0.y + a0.z*a0.z + a0.w*a0.w
                 + a1.x*a1.x + a1.y*a1.y + a1.z*a1.z + a1.w*a1.w
                 + b0.x*b0.x + b0.y*b0.y + b0.z*b0.z + b0.w*b0.w
                 + b1.x*b1.x + b1.y*b1.y + b1.z*b1.z + b1.w*b1.w;
        sq += __shfl_xor(sq, 16);
        sq += __shfl_xor(sq, 32);
        float sc = PRESCALE * rsqrtf(fmaxf(sq, 1e-24f));
        short8 f0, f1;
        f0[0]=bf16rne(a0.x*sc); f0[1]=bf16rne(a0.y*sc); f0[2]=bf16rne(a0.z*sc); f0[3]=bf16rne(a0.w*sc);
        f0[4]=bf16rne(a1.x*sc); f0[5]=bf16rne(a1.y*sc); f0[6]=bf16rne(a1.z*sc); f0[7]=bf16rne(a1.w*sc);
        f1[0]=bf16rne(b0.x*sc); f1[1]=bf16rne(b0.y*sc); f1[2]=bf16rne(b0.z*sc); f1[3]=bf16rne(b0.w*sc);
        f1[4]=bf16rne(b1.x*sc); f1[5]=bf16rne(b1.y*sc); f1[6]=bf16rne(b1.z*sc); f1[7]=bf16rne(b1.w*sc);
        pb[ch][0] = f0;
        pb[ch][1] = f1;
    }

    const f32x4 zero = {0.0f, 0.0f, 0.0f, 0.0f};

    // ---- row sweep: 32 tiles of 16 rows, stride 128 rows, 1-tile prefetch
    // tile i rows = (w + 8*i)*16; address delta per i = 8192 shorts = 1024 short8
    const short8* xp = reinterpret_cast<const short8*>(Xb + (w * 16 + lm) * DIM + lk * 8);
    short8 xb0 = xp[0];            // k 0..31 fragment
    short8 xb1 = xp[4];            // k 32..63 fragment (+32 shorts)
    float* prow = psum + blockIdx.x * NROWS + w * 16 + l;   // valid when l<16

    #pragma unroll 2
    for (int it = 0; it < 32; ++it) {
        const short8* xn = (it < 31) ? (xp + 1024) : xp;    // last iter: dummy reload
        short8 n0 = xn[0];
        short8 n1 = xn[4];

        float e0 = 0.f, e1 = 0.f, e2 = 0.f, e3 = 0.f;
        #pragma unroll
        for (int ch = 0; ch < NCH; ++ch) {
            f32x4 c = __builtin_amdgcn_mfma_f32_16x16x32_bf16(pb[ch][0], xb0, zero, 0, 0, 0);
            c = __builtin_amdgcn_mfma_f32_16x16x32_bf16(pb[ch][1], xb1, c, 0, 0, 0);
            e0 += __builtin_amdgcn_exp2f(c[0]);
            e1 += __builtin_amdgcn_exp2f(c[1]);
            e2 += __builtin_amdgcn_exp2f(c[2]);
            e3 += __builtin_amdgcn_exp2f(c[3]);
        }
        float s = (e0 + e1) + (e2 + e3);
        s += __shfl_xor(s, 16);
        s += __shfl_xor(s, 32);
        if (l < 16) prow[it * 128] = s;     // rows advance 128/iter

        xp = xn; xb0 = n0; xb1 = n1;
    }
}

// ---- per-row finish + global mean: out += sum_r (log(sum_b psum[b][r]) - st[r]) / N
__global__ void k_rowred(const float* __restrict__ psum, const float* __restrict__ st,
                         float* __restrict__ out) {
    __shared__ float red[256];
    int t = threadIdx.x;
    int r = blockIdx.x * 256 + t;
    float s = 0.0f;
    #pragma unroll 8
    for (int i = 0; i < NBLK; ++i)
        s += psum[i * NROWS + r];
    red[t] = (logf(s) - st[r]) * (1.0f / (float)NROWS);
    __syncthreads();
    #pragma unroll
    for (int off = 128; off > 0; off >>= 1) {
        if (t < off) red[t] += red[t + off];
        __syncthreads();
    }
    if (t == 0) atomicAdd(out, red[0]);
}

extern "C" void kernel_launch(void* const* d_in, const int* in_sizes, int n_in,
                              void* d_out, int out_size, void* d_ws, size_t ws_size,
                              hipStream_t stream) {
    const float* X = (const float*)d_in[0];
    const float* P = (const float*)d_in[1];
    const int*   T = (const int*)  d_in[3];   // d_in[2] = indices (unused)
    float* out = (float*)d_out;

    char* ws = (char*)d_ws;
    unsigned short* Xb = (unsigned short*)ws;                 // 512 KB
    float* st   = (float*)(ws + (512 << 10));                 // 16 KB
    float* psum = (float*)(ws + (1 << 20));                   // 8 MB (512 x 4096 f32)

    hipMemsetAsync(out, 0, sizeof(float), stream);
    k_prep  <<<NROWS / 4, 256, 0, stream>>>(X, P, T, Xb, st);
    k_main  <<<NBLK, 512, 0, stream>>>(P, Xb, psum);
    k_rowred<<<NROWS / 256, 256, 0, stream>>>(psum, st, out);
}

// Round 10
// 92.848 us; speedup vs baseline: 1.7082x; 1.0125x over previous
//
#include <hip/hip_runtime.h>
#include <math.h>

// ProxyNCA loss, MFMA version — round 10.
// logit_ic = 18 * xhat_i . phat_c ;  nll_i = log(sum_c exp(logit_ic)) - logit_{i,T_i}
// Both operands prescaled by sqrt(18*log2(e)) = 5.0959308 into bf16; the
// 16x16x32 bf16 MFMA accumulator holds log2(e)*logit, so exp = v_exp_f32.
//
// Round 10 vs round 9: R9 proved the plateau (68us, MfmaUtil 20%, VALU 43%,
// all pipes >55% idle) is LATENCY-bound per wave, not instruction count.
// At fixed 4 waves/SIMD:
//  - 2 independent row-tiles per iteration (16 iters x 32 MFMA + 64 exp):
//    tile-B MFMAs issue while tile-A exps/adds drain. Regs ~105 < 128 cap.
//  - shfl tail 2->1: single __shfl_xor(s,32), store 2 lane-group partials
//    per row (coalesced); k_rowred sums 1024 partials/row (psum 16 MB).
//  - no explicit X prefetch regs (2-tile ILP hides the ~200cyc L2 latency).
// Spill ledger (R2/R7/R8): only (512,2) configs never spilled. Keep (512,2).

#define NROWS 4096
#define NCLS  65536
#define DIM   64
#define CBLK  128                 // classes per block (register-resident P frags)
#define NBLK  (NCLS / CBLK)       // 512 blocks = 2/CU
#define NCH   (CBLK / 16)         // 8 MFMA chunks of 16 classes

typedef __attribute__((ext_vector_type(8))) short short8;
typedef __attribute__((ext_vector_type(4))) float f32x4;

#define PRESCALE 5.0959308f       // sqrt(18 * log2(e))

__device__ __forceinline__ short bf16rne(float f) {
    union { float f; unsigned u; } v; v.f = f;
    unsigned r = (v.u + 0x7fffu + ((v.u >> 16) & 1u)) >> 16;
    return (short)r;
}

// ---- per-row prep: Xb = bf16(PRESCALE * xhat), st[r] = exact f32 target logit
__global__ void k_prep(const float* __restrict__ X, const float* __restrict__ P,
                       const int* __restrict__ T,
                       unsigned short* __restrict__ Xb, float* __restrict__ st) {
    int row  = blockIdx.x * 4 + (threadIdx.x >> 6);
    int lane = threadIdx.x & 63;
    int tc   = T[row];
    float xv = X[row * DIM + lane];
    float pv = P[tc  * DIM + lane];
    float x2 = xv * xv, p2 = pv * pv, xp = xv * pv;
    #pragma unroll
    for (int off = 32; off > 0; off >>= 1) {
        x2 += __shfl_xor(x2, off);
        p2 += __shfl_xor(p2, off);
        xp += __shfl_xor(xp, off);
    }
    float rx = rsqrtf(fmaxf(x2, 1e-24f));
    Xb[row * DIM + lane] = (unsigned short)bf16rne(xv * (PRESCALE * rx));
    if (lane == 0)
        st[row] = 18.0f * xp * rx * rsqrtf(fmaxf(p2, 1e-24f));
}

// ---- main: block b owns classes [b*128,(b+1)*128); sweeps all 4096 rows ----
// 8 waves; wave w, iter it handles row-tiles (w+16it) and (w+16it+8).
// P frags normalized/converted once into 64 regs per wave.
// mfma(P_frag, X_frag): C col = lane&15 = x-row, regs = 4 classes.
// Epilogue per tile: one shfl_xor(32); lanes 0..31 store 2 partials/row.
__global__ __launch_bounds__(512, 2)
void k_main(const float* __restrict__ prox, const unsigned short* __restrict__ Xb,
            float* __restrict__ psum) {
    int t = threadIdx.x;
    int w = t >> 6;
    int l = t & 63;
    int cb = blockIdx.x * CBLK;
    int lm = l & 15;         // class-in-chunk (A row) / x-row (B col)
    int lk = l >> 4;         // k-group

    // ---- one-time: load 128 classes of P (f32), normalize, convert to frags
    short8 pb[NCH][2];
    #pragma unroll
    for (int ch = 0; ch < NCH; ++ch) {
        int cls = cb + ch * 16 + lm;
        const float4* pr = reinterpret_cast<const float4*>(prox + cls * DIM + lk * 8);
        float4 a0 = pr[0], a1 = pr[1];          // k = lk*8 .. +7
        const float4* pr2 = reinterpret_cast<const float4*>(prox + cls * DIM + 32 + lk * 8);
        float4 b0 = pr2[0], b1 = pr2[1];        // k = 32 + lk*8 .. +7
        float sq = a0.x*a0.x + a0.y*a0.y + a0.z*a0.z + a0.w*a0.w
                 + a1.x*a1.x + a1.y*a1.y + a1.z*a1.z + a1.w*a1.w
                 + b0.x*b0.x + b0.y*b0.y + b0.z*b0.z + b0.w*b0.w
                 + b1.x*b1.x + b1.y*b1.y + b1.z*b1.z + b1.w*b1.w;
        sq += __shfl_xor(sq, 16);
        sq += __shfl_xor(sq, 32);
        float sc = PRESCALE * rsqrtf(fmaxf(sq, 1e-24f));
        short8 f0, f1;
        f0[0]=bf16rne(a0.x*sc); f0[1]=bf16rne(a0.y*sc); f0[2]=bf16rne(a0.z*sc); f0[3]=bf16rne(a0.w*sc);
        f0[4]=bf16rne(a1.x*sc); f0[5]=bf16rne(a1.y*sc); f0[6]=bf16rne(a1.z*sc); f0[7]=bf16rne(a1.w*sc);
        f1[0]=bf16rne(b0.x*sc); f1[1]=bf16rne(b0.y*sc); f1[2]=bf16rne(b0.z*sc); f1[3]=bf16rne(b0.w*sc);
        f1[4]=bf16rne(b1.x*sc); f1[5]=bf16rne(b1.y*sc); f1[6]=bf16rne(b1.z*sc); f1[7]=bf16rne(b1.w*sc);
        pb[ch][0] = f0;
        pb[ch][1] = f1;
    }

    const f32x4 zero = {0.0f, 0.0f, 0.0f, 0.0f};

    // ---- row sweep: 16 iterations x 2 independent tiles (A: w+16it, B: +8)
    // A-tile rows advance 256/iter = 16384 shorts = 2048 short8.
    const short8* xpA = reinterpret_cast<const short8*>(Xb + (w * 16 + lm) * DIM + lk * 8);
    // psum layout: [block][row][2] f32; lane l<32 stores part lk at
    // ((bx*NROWS + row) * 2 + lk); row = tilebase + lm.
    float* prow = psum + ((size_t)blockIdx.x * NROWS + w * 16 + lm) * 2 + lk;

    #pragma unroll 1
    for (int it = 0; it < 16; ++it) {
        short8 xA0 = xpA[0];
        short8 xA1 = xpA[4];          // +32 shorts (k 32..63)
        short8 xB0 = xpA[1024];       // +8192 shorts = +128 rows
        short8 xB1 = xpA[1028];

        float eA0 = 0.f, eA1 = 0.f, eA2 = 0.f, eA3 = 0.f;
        float eB0 = 0.f, eB1 = 0.f, eB2 = 0.f, eB3 = 0.f;
        #pragma unroll
        for (int ch = 0; ch < NCH; ++ch) {
            f32x4 cA = __builtin_amdgcn_mfma_f32_16x16x32_bf16(pb[ch][0], xA0, zero, 0, 0, 0);
            cA = __builtin_amdgcn_mfma_f32_16x16x32_bf16(pb[ch][1], xA1, cA, 0, 0, 0);
            f32x4 cB = __builtin_amdgcn_mfma_f32_16x16x32_bf16(pb[ch][0], xB0, zero, 0, 0, 0);
            cB = __builtin_amdgcn_mfma_f32_16x16x32_bf16(pb[ch][1], xB1, cB, 0, 0, 0);
            eA0 += __builtin_amdgcn_exp2f(cA[0]);
            eA1 += __builtin_amdgcn_exp2f(cA[1]);
            eA2 += __builtin_amdgcn_exp2f(cA[2]);
            eA3 += __builtin_amdgcn_exp2f(cA[3]);
            eB0 += __builtin_amdgcn_exp2f(cB[0]);
            eB1 += __builtin_amdgcn_exp2f(cB[1]);
            eB2 += __builtin_amdgcn_exp2f(cB[2]);
            eB3 += __builtin_amdgcn_exp2f(cB[3]);
        }
        float sA = (eA0 + eA1) + (eA2 + eA3);
        float sB = (eB0 + eB1) + (eB2 + eB3);
        sA += __shfl_xor(sA, 32);     // lane holds partial over {lk, lk^2}
        sB += __shfl_xor(sB, 32);
        if (l < 32) {
            prow[0]       = sA;       // rows w*16+256*it .. +15, part lk
            prow[128 * 2] = sB;       // +128 rows
        }

        xpA += 2048;                  // +256 rows
        prow += 256 * 2;
    }
}

// ---- per-row finish + global mean: out += sum_r (log(sum psum[.,r,.]) - st[r])/N
__global__ void k_rowred(const float* __restrict__ psum, const float* __restrict__ st,
                         float* __restrict__ out) {
    __shared__ float red[256];
    int t = threadIdx.x;
    int r = blockIdx.x * 256 + t;
    const float2* p2 = reinterpret_cast<const float2*>(psum) + r;
    float s = 0.0f;
    #pragma unroll 8
    for (int i = 0; i < NBLK; ++i) {
        float2 v = p2[i * NROWS];
        s += v.x + v.y;
    }
    red[t] = (logf(s) - st[r]) * (1.0f / (float)NROWS);
    __syncthreads();
    #pragma unroll
    for (int off = 128; off > 0; off >>= 1) {
        if (t < off) red[t] += red[t + off];
        __syncthreads();
    }
    if (t == 0) atomicAdd(out, red[0]);
}

extern "C" void kernel_launch(void* const* d_in, const int* in_sizes, int n_in,
                              void* d_out, int out_size, void* d_ws, size_t ws_size,
                              hipStream_t stream) {
    const float* X = (const float*)d_in[0];
    const float* P = (const float*)d_in[1];
    const int*   T = (const int*)  d_in[3];   // d_in[2] = indices (unused)
    float* out = (float*)d_out;

    char* ws = (char*)d_ws;
    unsigned short* Xb = (unsigned short*)ws;                 // 512 KB
    float* st   = (float*)(ws + (512 << 10));                 // 16 KB
    float* psum = (float*)(ws + (1 << 20));                   // 16 MB (512 x 4096 x 2)

    hipMemsetAsync(out, 0, sizeof(float), stream);
    k_prep  <<<NROWS / 4, 256, 0, stream>>>(X, P, T, Xb, st);
    k_main  <<<NBLK, 512, 0, stream>>>(P, Xb, psum);
    k_rowred<<<NROWS / 256, 256, 0, stream>>>(psum, st, out);
}